// Round 6
// baseline (193.448 us; speedup 1.0000x reference)
//
#include <hip/hip_runtime.h>
#include <stdint.h>

// MultiHeadSelfAttention: B=2, T=2048, C=1024, H=16, Dk=64, fp32 in/out.
// R15: k_attn LDS-bandwidth fix. Accounting error found in R12/R14: one
//      ds_read_b128 moves 1KB per WAVE (64 lanes x 16B) at ~85 B/cyc/CU.
//      The 16-q-per-wave split doubled per-CU fragment traffic to 8.4 MB
//      (~98K cycles = 72% of runtime) -- the invariant limiter behind the
//      R12/R14 nulls. R15 restores R10's verified 32-q-per-wave body
//      (nb=2: ak/av reads amortize over 2x MFMAs) -> 4.2 MB/CU, while
//      keeping R14's wins: KVBLK=128 (half the barriers) and XCD
//      bh-grouping remap (FETCH 69.7->12.3 MB, K/V HBM-fetched once).
//      4 waves x 256 thr, 2 blocks/CU, LDS 64KB. GEMMs unchanged.

typedef __bf16 bf16;
typedef __bf16 bf16x8 __attribute__((ext_vector_type(8)));
typedef __bf16 bf16x4 __attribute__((ext_vector_type(4)));
typedef float  f32x4  __attribute__((ext_vector_type(4)));

#define SEQ_T 2048
#define CDIM 1024
#define BT   4096   // B*T

// async global->LDS, 16B per lane. LDS dest = wave-uniform base + lane*16.
__device__ __forceinline__ void gload16(const void* g, void* l) {
    __builtin_amdgcn_global_load_lds(
        (const __attribute__((address_space(1))) void*)(uintptr_t)g,
        (__attribute__((address_space(3))) void*)(uint32_t)(uintptr_t)l,
        16, 0, 0);
}

// ---------------------------------------------------------------- convert
__global__ __launch_bounds__(256) void k_convert(
    const float* __restrict__ x, const float* __restrict__ wqkv,
    const float* __restrict__ wout,
    bf16* __restrict__ xb, bf16* __restrict__ wqb, bf16* __restrict__ wob) {
    const int NX = (BT * CDIM) / 4;        // 1048576
    const int NQ = (3 * CDIM * CDIM) / 4;  // 786432
    const int NO = (CDIM * CDIM) / 4;      // 262144
    int i = blockIdx.x * 256 + threadIdx.x;
    const float4* src; bf16* dst; int j;
    if (i < NX)                    { src = (const float4*)x;    dst = xb;  j = i; }
    else if ((j = i - NX) < NQ)    { src = (const float4*)wqkv; dst = wqb; }
    else if ((j = i - NX - NQ) < NO) { src = (const float4*)wout; dst = wob; }
    else return;
    float4 v = src[j];
    bf16x4 o = { (bf16)v.x, (bf16)v.y, (bf16)v.z, (bf16)v.w };
    ((bf16x4*)dst)[j] = o;
}

// ------------------------------------------------------------- GEMM core
template <int BM, int BN, int MI, int NI>
__device__ __forceinline__ void gemm_core(
    const bf16* __restrict__ A, const bf16* __restrict__ Bw,
    bf16* As, bf16* Bs, int m0, int n0, int tid, f32x4 (&acc)[MI][NI]) {
    const int lane = tid & 63, wv = tid >> 6;
    const int quad = lane >> 4, lo = lane & 15;
    const int wm = (wv >> 1) * MI * 16, wn = (wv & 1) * NI * 16;
#pragma unroll
    for (int mi = 0; mi < MI; ++mi)
#pragma unroll
        for (int ni = 0; ni < NI; ++ni) acc[mi][ni] = 0.0f;

    for (int kk = 0; kk < 1024; kk += 32) {
        __syncthreads();
#pragma unroll
        for (int c = 0; c < BM / 64; ++c) {
            int slot = c * 256 + tid;
            int row = slot >> 2, sc = slot & 3;
            int g = sc ^ ((row >> 1) & 3);
            gload16(A + (m0 + row) * 1024 + kk + g * 8,
                    As + c * 2048 + (tid & 192) * 8);
        }
#pragma unroll
        for (int c = 0; c < BN / 64; ++c) {
            int slot = c * 256 + tid;
            int row = slot >> 2, sc = slot & 3;
            int g = sc ^ ((row >> 1) & 3);
            gload16(Bw + (n0 + row) * 1024 + kk + g * 8,
                    Bs + c * 2048 + (tid & 192) * 8);
        }
        __syncthreads();
        bf16x8 af[MI], bb[NI];
#pragma unroll
        for (int mi = 0; mi < MI; ++mi) {
            int row = wm + mi * 16 + lo;
            int ch = quad ^ ((row >> 1) & 3);
            af[mi] = *(const bf16x8*)(As + row * 32 + ch * 8);
        }
#pragma unroll
        for (int ni = 0; ni < NI; ++ni) {
            int row = wn + ni * 16 + lo;
            int ch = quad ^ ((row >> 1) & 3);
            bb[ni] = *(const bf16x8*)(Bs + row * 32 + ch * 8);
        }
#pragma unroll
        for (int mi = 0; mi < MI; ++mi)
#pragma unroll
            for (int ni = 0; ni < NI; ++ni)
                acc[mi][ni] = __builtin_amdgcn_mfma_f32_16x16x32_bf16(
                    af[mi], bb[ni], acc[mi][ni], 0, 0, 0);
    }
}

// ------------------------------------------------------------- QKV GEMM
__global__ __launch_bounds__(256) void k_gemm_qkv(
    const bf16* __restrict__ A, const bf16* __restrict__ Bw,
    const float* __restrict__ bias,
    bf16* __restrict__ qb, bf16* __restrict__ kb, bf16* __restrict__ vt) {
    __shared__ __align__(16) char pool[18432];   // As 8K | Bs 8K ; reused as T
    bf16* As = (bf16*)pool;
    bf16* Bs = (bf16*)(pool + 8192);
    bf16* T  = (bf16*)pool;                      // [64][136] = 17408 B
    const int tid = threadIdx.x;
    const int m0 = blockIdx.y * 128, n0 = blockIdx.x * 128;
    f32x4 acc[4][4];
    gemm_core<128, 128, 4, 4>(A, Bw, As, Bs, m0, n0, tid, acc);
    const int lane = tid & 63, wv = tid >> 6;
    const int quad = lane >> 4, lo = lane & 15;
    const int wm = (wv >> 1) * 64, wn = (wv & 1) * 64;
    const int which = n0 >> 10;
    if (which == 2) {
        // V transposed: two n-half passes. Owner waves (wn/64==p) write
        // T[n_local][m] with b64 (m packed per lane); all read out rows
        // n -> m(t)-contiguous -> coalesced 16B stores to vt[b,h,d,t].
        const int b = m0 >> 11, tt0 = m0 & 2047;
#pragma unroll
        for (int p = 0; p < 2; ++p) {
            __syncthreads();
            if ((wv & 1) == p) {
#pragma unroll
                for (int ni = 0; ni < 4; ++ni) {
                    int nl = ni * 16 + lo;
                    float bv = bias[n0 + wn + nl];
#pragma unroll
                    for (int mi = 0; mi < 4; ++mi) {
                        bf16x4 v4;
#pragma unroll
                        for (int r = 0; r < 4; ++r)
                            v4[r] = (bf16)(acc[mi][ni][r] + bv);
                        *(bf16x4*)(T + nl * 136 + wm + mi * 16 + quad * 4) = v4;
                    }
                }
            }
            __syncthreads();
#pragma unroll
            for (int pass = 0; pass < 4; ++pass) {
                int chunk = pass * 256 + tid;
                int nl = chunk >> 4, mc = chunk & 15;
                bf16x8 v = *(const bf16x8*)(T + nl * 136 + mc * 8);
                int n_g = n0 + p * 64 + nl;
                int h = (n_g >> 6) & 15, d = n_g & 63;
                *(bf16x8*)(vt + ((size_t)(b * 16 + h) * 64 + d) * 2048 +
                           tt0 + mc * 8) = v;
            }
        }
    } else {
        bf16* dst = which == 0 ? qb : kb;
        const float scale = which == 0 ? 0.125f * 1.44269504089f : 1.0f;
        // two m-half passes through LDS transpose buffer
#pragma unroll
        for (int p = 0; p < 2; ++p) {
            __syncthreads();
            if ((wv >> 1) == p) {   // waves holding m-rows [p*64, p*64+64)
#pragma unroll
                for (int ni = 0; ni < 4; ++ni) {
                    int n = wn + ni * 16 + lo;
                    float bv = bias[n0 + n];
#pragma unroll
                    for (int mi = 0; mi < 4; ++mi) {
#pragma unroll
                        for (int r = 0; r < 4; ++r) {
                            int ml = mi * 16 + quad * 4 + r;
                            T[ml * 136 + n] =
                                (bf16)((acc[mi][ni][r] + bv) * scale);
                        }
                    }
                }
            }
            __syncthreads();
#pragma unroll
            for (int pass = 0; pass < 4; ++pass) {
                int chunk = pass * 256 + tid;
                int ml = chunk >> 4, nc = chunk & 15;
                bf16x8 v = *(const bf16x8*)(T + ml * 136 + nc * 8);
                int n_g = n0 + nc * 8;
                int h = (n_g >> 6) & 15, d = n_g & 63;
                int t = m0 + p * 64 + ml;
                int b = t >> 11, tt = t & 2047;
                *(bf16x8*)(dst + ((size_t)(b * 16 + h) * 2048 + tt) * 64 + d) = v;
            }
        }
    }
}

// ------------------------------------------------------------ out-proj GEMM
__global__ __launch_bounds__(256) void k_gemm_out(
    const bf16* __restrict__ A, const bf16* __restrict__ Bw,
    const float* __restrict__ bias, float* __restrict__ out) {
    __shared__ __align__(16) bf16 As[128 * 32];
    __shared__ __align__(16) bf16 Bs[64 * 32];
    const int tid = threadIdx.x;
    const int m0 = blockIdx.y * 128, n0 = blockIdx.x * 64;
    f32x4 acc[4][2];
    gemm_core<128, 64, 4, 2>(A, Bw, As, Bs, m0, n0, tid, acc);
    const int lane = tid & 63, wv = tid >> 6;
    const int quad = lane >> 4, lo = lane & 15;
    const int wm = (wv >> 1) * 64, wn = (wv & 1) * 32;
#pragma unroll
    for (int ni = 0; ni < 2; ++ni) {
        int n = n0 + wn + ni * 16 + lo;
        float bv = bias[n];
#pragma unroll
        for (int mi = 0; mi < 4; ++mi) {
#pragma unroll
            for (int r = 0; r < 4; ++r) {
                int m = m0 + wm + mi * 16 + quad * 4 + r;
                out[(size_t)m * 1024 + n] = acc[mi][ni][r] + bv;
            }
        }
    }
}

// ---------------------------------------------------------- flash attention
// R15: 4 waves (256 thr), wave wv owns q-rows [q0 + wv*32, +32) (R10's
// verified nb=2 body). In-register P via key permutation pi(sb,lo) =
// (sb&1)*32 + (lo>>2)*8 + (sb>>1)*4 + (lo&3). KVBLK=128: staged tile = 2
// key-halves, the 64-key body runs per half. XCD bh-grouping remap (R14):
// 4 whole bh per XCD -> K/V L2-resident, HBM-fetched once.
// Per-CU LDS fragment traffic: 8 waves x 32 bodies x 16KB = 4.2 MB (half
// of R14's 8.4 MB -- the measured limiter).
// LDS: Ks 2x16K + Vs 2x16K = 64KB. Grid 512 x 256thr (2 blocks/CU).
__global__ __launch_bounds__(256, 2) void k_attn(
    const bf16* __restrict__ qg, const bf16* __restrict__ kg,
    const bf16* __restrict__ vtg, bf16* __restrict__ og) {
    __shared__ __align__(16) bf16 Ks[2][2][64 * 64];  // [buf][khalf][k][d]
    __shared__ __align__(16) bf16 Vs[2][2][64 * 64];  // [buf][shalf][d][s]
    const int tid = threadIdx.x, lane = tid & 63, wv = tid >> 6;
    const int quad = lane >> 4, lo = lane & 15;
    // XCD-grouping remap (bijective over 512 = 8 xcd x 4 bh x 16 qb):
    const int flat = blockIdx.y * 16 + blockIdx.x;   // == hw dispatch order
    const int bh = ((flat & 7) << 2) | ((flat >> 3) >> 4);
    const int q0 = ((flat >> 3) & 15) * 128;
    const bf16* Qb = qg + (size_t)bh * 2048 * 64;
    const bf16* Kb = kg + (size_t)bh * 2048 * 64;
    const bf16* Vb = vtg + (size_t)bh * 64 * 2048;

    // staging lane->address terms (R10 exact: two 64-row chunks per half).
    const int srow = tid >> 3, ssc = tid & 7;
    const int sgv0 = ssc ^ (srow & 7);                               // V swz
    const int srow1 = (256 + tid) >> 3;
    const int sgv1 = ssc ^ (srow1 & 7);
    const int sgk0 = ssc ^ ((((srow >> 3) & 1) << 2) | (srow & 3));  // K swz
    const int sgk1 = ssc ^ ((((srow1 >> 3) & 1) << 2) | (srow1 & 3));
    const int sbase = (tid & 192) * 8;

    // K fragment read terms (R10 exact)
    const int swk = (((lo >> 2) & 1) << 2) | (lo & 3);
    const int prow = ((lo >> 2) << 3) | (lo & 3);

    // Q B-fragments: loop-invariant, straight from global into 16 VGPRs.
    bf16x8 bq[2][2];
#pragma unroll
    for (int nb = 0; nb < 2; ++nb)
#pragma unroll
        for (int ks = 0; ks < 2; ++ks)
            bq[nb][ks] = *(const bf16x8*)(
                Qb + (size_t)(q0 + wv * 32 + nb * 16 + lo) * 64 + ks * 32 + quad * 8);

    bf16x8 ones;
#pragma unroll
    for (int j = 0; j < 8; ++j) ones[j] = (bf16)1.0f;

    f32x4 oaccT[4][2];  // O^T: [d-block][q-block], col=q=lo, row=d=quad*4+r
    f32x4 osum[2];      // denominator, col=q=lo
#pragma unroll
    for (int db = 0; db < 4; ++db)
#pragma unroll
        for (int nb = 0; nb < 2; ++nb) oaccT[db][nb] = 0.0f;
    osum[0] = 0.0f; osum[1] = 0.0f;

    // prefetch tile 0 into buf 0 (keys [0,128), both halves)
#pragma unroll
    for (int h = 0; h < 2; ++h) {
        gload16(Kb + (h * 64 + srow) * 64 + sgk0 * 8,  &Ks[0][h][0] + sbase);
        gload16(Kb + (h * 64 + srow1) * 64 + sgk1 * 8, &Ks[0][h][0] + 2048 + sbase);
        gload16(Vb + (size_t)srow * 2048 + h * 64 + sgv0 * 8,
                &Vs[0][h][0] + sbase);
        gload16(Vb + (size_t)srow1 * 2048 + h * 64 + sgv1 * 8,
                &Vs[0][h][0] + 2048 + sbase);
    }

    for (int i = 0; i < SEQ_T / 128; ++i) {
        const int buf = i & 1;
        __syncthreads();  // prev reads of buf^1 done + vmcnt drain of DMA_i
        if (i + 1 < SEQ_T / 128) {
            const int t0 = (i + 1) * 128;
#pragma unroll
            for (int h = 0; h < 2; ++h) {
                gload16(Kb + (t0 + h * 64 + srow) * 64 + sgk0 * 8,
                        &Ks[buf ^ 1][h][0] + sbase);
                gload16(Kb + (t0 + h * 64 + srow1) * 64 + sgk1 * 8,
                        &Ks[buf ^ 1][h][0] + 2048 + sbase);
                gload16(Vb + (size_t)srow * 2048 + t0 + h * 64 + sgv0 * 8,
                        &Vs[buf ^ 1][h][0] + sbase);
                gload16(Vb + (size_t)srow1 * 2048 + t0 + h * 64 + sgv1 * 8,
                        &Vs[buf ^ 1][h][0] + 2048 + sbase);
            }
        }

#pragma unroll
        for (int hh = 0; hh < 2; ++hh) {
            const bf16* KsB = &Ks[buf][hh][0];
            const bf16* VsB = &Vs[buf][hh][0];

            // S^T = K*Q^T with permuted key rows (keys of this half).
            f32x4 sacc[4][2];
#pragma unroll
            for (int sb = 0; sb < 4; ++sb)
#pragma unroll
                for (int nb = 0; nb < 2; ++nb) sacc[sb][nb] = 0.0f;
#pragma unroll
            for (int ks = 0; ks < 2; ++ks) {
                int c = ks * 4 + quad;
                bf16x8 ak[4];
#pragma unroll
                for (int sb = 0; sb < 4; ++sb) {
                    int row = ((sb & 1) << 5) + ((sb >> 1) << 2) + prow;
                    ak[sb] = *(const bf16x8*)(KsB + row * 64 + ((c ^ swk) * 8));
                }
#pragma unroll
                for (int sb = 0; sb < 4; ++sb)
#pragma unroll
                    for (int nb = 0; nb < 2; ++nb)
                        sacc[sb][nb] = __builtin_amdgcn_mfma_f32_16x16x32_bf16(
                            ak[sb], bq[nb][ks], sacc[sb][nb], 0, 0, 0);
            }

            // P = exp2(S^T) packed in registers (R10 mapping).
            bf16x8 bp[2][2];
#pragma unroll
            for (int nb = 0; nb < 2; ++nb)
#pragma unroll
                for (int ks2 = 0; ks2 < 2; ++ks2) {
                    bf16x8 p;
#pragma unroll
                    for (int s2 = 0; s2 < 2; ++s2)
#pragma unroll
                        for (int r = 0; r < 4; ++r)
                            p[s2 * 4 + r] = (bf16)exp2f(sacc[s2 * 2 + ks2][nb][r]);
                    bp[ks2][nb] = p;
                }

            // O^T += V^T * P^T ; denom += ones * P^T
#pragma unroll
            for (int ks2 = 0; ks2 < 2; ++ks2) {
                bf16x8 av[4];
#pragma unroll
                for (int db = 0; db < 4; ++db) {
                    int row = db * 16 + lo;
                    av[db] = *(const bf16x8*)(VsB + row * 64 +
                                              (((ks2 * 4 + quad) ^ (row & 7)) * 8));
                }
#pragma unroll
                for (int nb = 0; nb < 2; ++nb)
                    osum[nb] = __builtin_amdgcn_mfma_f32_16x16x32_bf16(
                        ones, bp[ks2][nb], osum[nb], 0, 0, 0);
#pragma unroll
                for (int db = 0; db < 4; ++db)
#pragma unroll
                    for (int nb = 0; nb < 2; ++nb)
                        oaccT[db][nb] = __builtin_amdgcn_mfma_f32_16x16x32_bf16(
                            av[db], bp[ks2][nb], oaccT[db][nb], 0, 0, 0);
            }
        }
    }

    // epilogue: O^T/denom -> attn_out [b, t, h*64+d]; packed 8B stores.
    const int b = bh >> 4, h = bh & 15;
#pragma unroll
    for (int nb = 0; nb < 2; ++nb) {
        float inv = 1.0f / osum[nb][0];
        int t = q0 + wv * 32 + nb * 16 + lo;
#pragma unroll
        for (int db = 0; db < 4; ++db) {
            bf16x4 o4;
#pragma unroll
            for (int r = 0; r < 4; ++r) o4[r] = (bf16)(oaccT[db][nb][r] * inv);
            *(bf16x4*)(og + ((size_t)b * 2048 + t) * 1024 + h * 64 + db * 16 + quad * 4) = o4;
        }
    }
}

// ---------------------------------------------------------------- launcher
extern "C" void kernel_launch(void* const* d_in, const int* in_sizes, int n_in,
                              void* d_out, int out_size, void* d_ws, size_t ws_size,
                              hipStream_t stream) {
    const float* x     = (const float*)d_in[0];
    const float* qkv_w = (const float*)d_in[1];
    const float* qkv_b = (const float*)d_in[2];
    const float* out_w = (const float*)d_in[3];
    const float* out_b = (const float*)d_in[4];
    float* out = (float*)d_out;
    char* ws = (char*)d_ws;
    // ws layout (48 MB total)
    bf16* xb  = (bf16*)(ws);                       // 8 MB  [4096][1024]
    bf16* wqb = (bf16*)(ws + 8388608);             // 6 MB  [3072][1024]
    bf16* wob = (bf16*)(ws + 14680064);            // 2 MB  [1024][1024]
    bf16* qb  = (bf16*)(ws + 16777216);            // 8 MB  [b,h,t,d]
    bf16* kb  = (bf16*)(ws + 25165824);            // 8 MB  [b,h,t,d]
    bf16* vt  = (bf16*)(ws + 33554432);            // 8 MB  [b,h,d,t]
    bf16* ao  = (bf16*)(ws + 41943040);            // 8 MB  [4096][1024]

    k_convert<<<8192, 256, 0, stream>>>(x, qkv_w, out_w, xb, wqb, wob);
    k_gemm_qkv<<<dim3(24, 32), 256, 0, stream>>>(xb, wqb, qkv_b, qb, kb, vt);
    k_attn<<<dim3(16, 32), 256, 0, stream>>>(qb, kb, vt, ao);
    k_gemm_out<<<dim3(16, 32), 256, 0, stream>>>(ao, wob, out_b, out);
}

// Round 7
// 184.646 us; speedup vs baseline: 1.0477x; 1.0477x over previous
//
#include <hip/hip_runtime.h>
#include <stdint.h>

// MultiHeadSelfAttention: B=2, T=2048, C=1024, H=16, Dk=64, fp32 in/out.
// R16 = R14 (best verified config: 57.2us attn / 185.5us total) + T5
//      s_setprio around MFMA clusters (m191: +4-7% attn in multi-wave
//      independent-phase regime). R15's LDS-bandwidth theory was refuted
//      (halving LDS traffic regressed 57->64us via occupancy/VGPR); R14's
//      8-wave 16-q lean-wave point is the structural optimum found.
// R14: (a) XCD bh-grouping remap: 4 whole bh per XCD (2MB K/V in 4MB L2)
//      -> FETCH 69.7->12.3MB, K/V HBM-fetched once. (b) KVBLK=128, LDS
//      64KB, 2 blocks/CU. In-register P via key permutation (R10/R12).

typedef __bf16 bf16;
typedef __bf16 bf16x8 __attribute__((ext_vector_type(8)));
typedef __bf16 bf16x4 __attribute__((ext_vector_type(4)));
typedef float  f32x4  __attribute__((ext_vector_type(4)));

#define SEQ_T 2048
#define CDIM 1024
#define BT   4096   // B*T

// async global->LDS, 16B per lane. LDS dest = wave-uniform base + lane*16.
__device__ __forceinline__ void gload16(const void* g, void* l) {
    __builtin_amdgcn_global_load_lds(
        (const __attribute__((address_space(1))) void*)(uintptr_t)g,
        (__attribute__((address_space(3))) void*)(uint32_t)(uintptr_t)l,
        16, 0, 0);
}

// ---------------------------------------------------------------- convert
__global__ __launch_bounds__(256) void k_convert(
    const float* __restrict__ x, const float* __restrict__ wqkv,
    const float* __restrict__ wout,
    bf16* __restrict__ xb, bf16* __restrict__ wqb, bf16* __restrict__ wob) {
    const int NX = (BT * CDIM) / 4;        // 1048576
    const int NQ = (3 * CDIM * CDIM) / 4;  // 786432
    const int NO = (CDIM * CDIM) / 4;      // 262144
    int i = blockIdx.x * 256 + threadIdx.x;
    const float4* src; bf16* dst; int j;
    if (i < NX)                    { src = (const float4*)x;    dst = xb;  j = i; }
    else if ((j = i - NX) < NQ)    { src = (const float4*)wqkv; dst = wqb; }
    else if ((j = i - NX - NQ) < NO) { src = (const float4*)wout; dst = wob; }
    else return;
    float4 v = src[j];
    bf16x4 o = { (bf16)v.x, (bf16)v.y, (bf16)v.z, (bf16)v.w };
    ((bf16x4*)dst)[j] = o;
}

// ------------------------------------------------------------- GEMM core
template <int BM, int BN, int MI, int NI>
__device__ __forceinline__ void gemm_core(
    const bf16* __restrict__ A, const bf16* __restrict__ Bw,
    bf16* As, bf16* Bs, int m0, int n0, int tid, f32x4 (&acc)[MI][NI]) {
    const int lane = tid & 63, wv = tid >> 6;
    const int quad = lane >> 4, lo = lane & 15;
    const int wm = (wv >> 1) * MI * 16, wn = (wv & 1) * NI * 16;
#pragma unroll
    for (int mi = 0; mi < MI; ++mi)
#pragma unroll
        for (int ni = 0; ni < NI; ++ni) acc[mi][ni] = 0.0f;

    for (int kk = 0; kk < 1024; kk += 32) {
        __syncthreads();
#pragma unroll
        for (int c = 0; c < BM / 64; ++c) {
            int slot = c * 256 + tid;
            int row = slot >> 2, sc = slot & 3;
            int g = sc ^ ((row >> 1) & 3);
            gload16(A + (m0 + row) * 1024 + kk + g * 8,
                    As + c * 2048 + (tid & 192) * 8);
        }
#pragma unroll
        for (int c = 0; c < BN / 64; ++c) {
            int slot = c * 256 + tid;
            int row = slot >> 2, sc = slot & 3;
            int g = sc ^ ((row >> 1) & 3);
            gload16(Bw + (n0 + row) * 1024 + kk + g * 8,
                    Bs + c * 2048 + (tid & 192) * 8);
        }
        __syncthreads();
        bf16x8 af[MI], bb[NI];
#pragma unroll
        for (int mi = 0; mi < MI; ++mi) {
            int row = wm + mi * 16 + lo;
            int ch = quad ^ ((row >> 1) & 3);
            af[mi] = *(const bf16x8*)(As + row * 32 + ch * 8);
        }
#pragma unroll
        for (int ni = 0; ni < NI; ++ni) {
            int row = wn + ni * 16 + lo;
            int ch = quad ^ ((row >> 1) & 3);
            bb[ni] = *(const bf16x8*)(Bs + row * 32 + ch * 8);
        }
#pragma unroll
        for (int mi = 0; mi < MI; ++mi)
#pragma unroll
            for (int ni = 0; ni < NI; ++ni)
                acc[mi][ni] = __builtin_amdgcn_mfma_f32_16x16x32_bf16(
                    af[mi], bb[ni], acc[mi][ni], 0, 0, 0);
    }
}

// ------------------------------------------------------------- QKV GEMM
__global__ __launch_bounds__(256) void k_gemm_qkv(
    const bf16* __restrict__ A, const bf16* __restrict__ Bw,
    const float* __restrict__ bias,
    bf16* __restrict__ qb, bf16* __restrict__ kb, bf16* __restrict__ vt) {
    __shared__ __align__(16) char pool[18432];   // As 8K | Bs 8K ; reused as T
    bf16* As = (bf16*)pool;
    bf16* Bs = (bf16*)(pool + 8192);
    bf16* T  = (bf16*)pool;                      // [64][136] = 17408 B
    const int tid = threadIdx.x;
    const int m0 = blockIdx.y * 128, n0 = blockIdx.x * 128;
    f32x4 acc[4][4];
    gemm_core<128, 128, 4, 4>(A, Bw, As, Bs, m0, n0, tid, acc);
    const int lane = tid & 63, wv = tid >> 6;
    const int quad = lane >> 4, lo = lane & 15;
    const int wm = (wv >> 1) * 64, wn = (wv & 1) * 64;
    const int which = n0 >> 10;
    if (which == 2) {
        // V transposed: two n-half passes. Owner waves (wn/64==p) write
        // T[n_local][m] with b64 (m packed per lane); all read out rows
        // n -> m(t)-contiguous -> coalesced 16B stores to vt[b,h,d,t].
        const int b = m0 >> 11, tt0 = m0 & 2047;
#pragma unroll
        for (int p = 0; p < 2; ++p) {
            __syncthreads();
            if ((wv & 1) == p) {
#pragma unroll
                for (int ni = 0; ni < 4; ++ni) {
                    int nl = ni * 16 + lo;
                    float bv = bias[n0 + wn + nl];
#pragma unroll
                    for (int mi = 0; mi < 4; ++mi) {
                        bf16x4 v4;
#pragma unroll
                        for (int r = 0; r < 4; ++r)
                            v4[r] = (bf16)(acc[mi][ni][r] + bv);
                        *(bf16x4*)(T + nl * 136 + wm + mi * 16 + quad * 4) = v4;
                    }
                }
            }
            __syncthreads();
#pragma unroll
            for (int pass = 0; pass < 4; ++pass) {
                int chunk = pass * 256 + tid;
                int nl = chunk >> 4, mc = chunk & 15;
                bf16x8 v = *(const bf16x8*)(T + nl * 136 + mc * 8);
                int n_g = n0 + p * 64 + nl;
                int h = (n_g >> 6) & 15, d = n_g & 63;
                *(bf16x8*)(vt + ((size_t)(b * 16 + h) * 64 + d) * 2048 +
                           tt0 + mc * 8) = v;
            }
        }
    } else {
        bf16* dst = which == 0 ? qb : kb;
        const float scale = which == 0 ? 0.125f * 1.44269504089f : 1.0f;
        // two m-half passes through LDS transpose buffer
#pragma unroll
        for (int p = 0; p < 2; ++p) {
            __syncthreads();
            if ((wv >> 1) == p) {   // waves holding m-rows [p*64, p*64+64)
#pragma unroll
                for (int ni = 0; ni < 4; ++ni) {
                    int n = wn + ni * 16 + lo;
                    float bv = bias[n0 + n];
#pragma unroll
                    for (int mi = 0; mi < 4; ++mi) {
#pragma unroll
                        for (int r = 0; r < 4; ++r) {
                            int ml = mi * 16 + quad * 4 + r;
                            T[ml * 136 + n] =
                                (bf16)((acc[mi][ni][r] + bv) * scale);
                        }
                    }
                }
            }
            __syncthreads();
#pragma unroll
            for (int pass = 0; pass < 4; ++pass) {
                int chunk = pass * 256 + tid;
                int ml = chunk >> 4, nc = chunk & 15;
                bf16x8 v = *(const bf16x8*)(T + ml * 136 + nc * 8);
                int n_g = n0 + nc * 8;
                int h = (n_g >> 6) & 15, d = n_g & 63;
                int t = m0 + p * 64 + ml;
                int b = t >> 11, tt = t & 2047;
                *(bf16x8*)(dst + ((size_t)(b * 16 + h) * 2048 + tt) * 64 + d) = v;
            }
        }
    }
}

// ------------------------------------------------------------ out-proj GEMM
__global__ __launch_bounds__(256) void k_gemm_out(
    const bf16* __restrict__ A, const bf16* __restrict__ Bw,
    const float* __restrict__ bias, float* __restrict__ out) {
    __shared__ __align__(16) bf16 As[128 * 32];
    __shared__ __align__(16) bf16 Bs[64 * 32];
    const int tid = threadIdx.x;
    const int m0 = blockIdx.y * 128, n0 = blockIdx.x * 64;
    f32x4 acc[4][2];
    gemm_core<128, 64, 4, 2>(A, Bw, As, Bs, m0, n0, tid, acc);
    const int lane = tid & 63, wv = tid >> 6;
    const int quad = lane >> 4, lo = lane & 15;
    const int wm = (wv >> 1) * 64, wn = (wv & 1) * 32;
#pragma unroll
    for (int ni = 0; ni < 2; ++ni) {
        int n = n0 + wn + ni * 16 + lo;
        float bv = bias[n];
#pragma unroll
        for (int mi = 0; mi < 4; ++mi) {
#pragma unroll
            for (int r = 0; r < 4; ++r) {
                int m = m0 + wm + mi * 16 + quad * 4 + r;
                out[(size_t)m * 1024 + n] = acc[mi][ni][r] + bv;
            }
        }
    }
}

// ---------------------------------------------------------- flash attention
// R16: 8 waves (512 thr), wave wv owns q-rows [q0 + wv*16, +16); in-register
// P via key permutation pi(sb,lo) = (sb&1)*32 + (lo>>2)*8 + (sb>>1)*4 +
// (lo&3) (R12, verified). KVBLK=128: each staged tile = 2 key-halves, the
// verified 64-key body runs per half. Block remap groups 4 whole bh per
// XCD (flat&7 = XCD under round-robin dispatch): per-XCD K/V working set
// 2 MB in 4 MB L2 -> K/V HBM-fetched once, staging served from L2.
// T5: s_setprio(1) around QK and PV MFMA clusters (scheduler hint only).
// LDS: Ks 2x16K + Vs 2x16K = 64KB. Grid 512 x 512thr (2 blocks/CU).
__global__ __launch_bounds__(512, 4) void k_attn(
    const bf16* __restrict__ qg, const bf16* __restrict__ kg,
    const bf16* __restrict__ vtg, bf16* __restrict__ og) {
    __shared__ __align__(16) bf16 Ks[2][2][64 * 64];  // [buf][khalf][k][d]
    __shared__ __align__(16) bf16 Vs[2][2][64 * 64];  // [buf][shalf][d][s]
    const int tid = threadIdx.x, lane = tid & 63, wv = tid >> 6;
    const int quad = lane >> 4, lo = lane & 15;
    // XCD-grouping remap (bijective over 512 = 8 xcd x 4 bh x 16 qb):
    const int flat = blockIdx.y * 16 + blockIdx.x;   // == hw dispatch order
    const int bh = ((flat & 7) << 2) | ((flat >> 3) >> 4);
    const int q0 = ((flat >> 3) & 15) * 128;
    const bf16* Qb = qg + (size_t)bh * 2048 * 64;
    const bf16* Kb = kg + (size_t)bh * 2048 * 64;
    const bf16* Vb = vtg + (size_t)bh * 64 * 2048;

    // staging lane->address terms: 2 K + 2 V gloads per thread per tile.
    const int srow = tid >> 3, ssc = tid & 7;          // rows 0..63
    const int sgv = ssc ^ (srow & 7);                  // V swizzle
    const int sgk = ssc ^ ((((srow >> 3) & 1) << 2) | (srow & 3));  // K swizzle
    const int sbase = (tid & 448) * 8;                 // wave*512 elements

    // K fragment read terms (R12 exact)
    const int swk = (((lo >> 2) & 1) << 2) | (lo & 3);
    const int prow = ((lo >> 2) << 3) | (lo & 3);

    // Q B-fragments: loop-invariant, straight from global into 8 VGPRs.
    bf16x8 bq[2];
#pragma unroll
    for (int ks = 0; ks < 2; ++ks)
        bq[ks] = *(const bf16x8*)(
            Qb + (size_t)(q0 + wv * 16 + lo) * 64 + ks * 32 + quad * 8);

    bf16x8 ones;
#pragma unroll
    for (int j = 0; j < 8; ++j) ones[j] = (bf16)1.0f;

    f32x4 oaccT[4];   // O^T: [d-block], col=q=lo, row=d=quad*4+r
    f32x4 osum;       // denominator, col=q=lo
#pragma unroll
    for (int db = 0; db < 4; ++db) oaccT[db] = 0.0f;
    osum = 0.0f;

    // prefetch tile 0 into buf 0 (keys [0,128))
    gload16(Kb + srow * 64 + sgk * 8,                 &Ks[0][0][0] + sbase);
    gload16(Kb + (64 + srow) * 64 + sgk * 8,          &Ks[0][1][0] + sbase);
    gload16(Vb + (size_t)srow * 2048 + sgv * 8,       &Vs[0][0][0] + sbase);
    gload16(Vb + (size_t)srow * 2048 + 64 + sgv * 8,  &Vs[0][1][0] + sbase);

    for (int i = 0; i < SEQ_T / 128; ++i) {
        const int buf = i & 1;
        __syncthreads();  // prev reads of buf^1 done + vmcnt drain of DMA_i
        if (i + 1 < SEQ_T / 128) {
            const int t0 = (i + 1) * 128;
            gload16(Kb + (t0 + srow) * 64 + sgk * 8,
                    &Ks[buf ^ 1][0][0] + sbase);
            gload16(Kb + (t0 + 64 + srow) * 64 + sgk * 8,
                    &Ks[buf ^ 1][1][0] + sbase);
            gload16(Vb + (size_t)srow * 2048 + t0 + sgv * 8,
                    &Vs[buf ^ 1][0][0] + sbase);
            gload16(Vb + (size_t)srow * 2048 + t0 + 64 + sgv * 8,
                    &Vs[buf ^ 1][1][0] + sbase);
        }

#pragma unroll
        for (int hh = 0; hh < 2; ++hh) {
            const bf16* KsB = &Ks[buf][hh][0];
            const bf16* VsB = &Vs[buf][hh][0];

            // S^T = K*Q^T with permuted key rows (keys of this half).
            f32x4 sacc[4];
#pragma unroll
            for (int sb = 0; sb < 4; ++sb) sacc[sb] = 0.0f;
#pragma unroll
            for (int ks = 0; ks < 2; ++ks) {
                int c = ks * 4 + quad;
                bf16x8 ak[4];
#pragma unroll
                for (int sb = 0; sb < 4; ++sb) {
                    int row = ((sb & 1) << 5) + ((sb >> 1) << 2) + prow;
                    ak[sb] = *(const bf16x8*)(KsB + row * 64 + ((c ^ swk) * 8));
                }
                __builtin_amdgcn_s_setprio(1);
#pragma unroll
                for (int sb = 0; sb < 4; ++sb)
                    sacc[sb] = __builtin_amdgcn_mfma_f32_16x16x32_bf16(
                        ak[sb], bq[ks], sacc[sb], 0, 0, 0);
                __builtin_amdgcn_s_setprio(0);
            }

            // P = exp2(S^T) packed in registers (R12 mapping).
            bf16x8 bp[2];
#pragma unroll
            for (int ks2 = 0; ks2 < 2; ++ks2) {
                bf16x8 p;
#pragma unroll
                for (int s2 = 0; s2 < 2; ++s2)
#pragma unroll
                    for (int r = 0; r < 4; ++r)
                        p[s2 * 4 + r] = (bf16)exp2f(sacc[s2 * 2 + ks2][r]);
                bp[ks2] = p;
            }

            // O^T += V^T * P^T ; denom += ones * P^T
#pragma unroll
            for (int ks2 = 0; ks2 < 2; ++ks2) {
                bf16x8 av[4];
#pragma unroll
                for (int db = 0; db < 4; ++db) {
                    int row = db * 16 + lo;
                    av[db] = *(const bf16x8*)(VsB + row * 64 +
                                              (((ks2 * 4 + quad) ^ (row & 7)) * 8));
                }
                __builtin_amdgcn_s_setprio(1);
                osum = __builtin_amdgcn_mfma_f32_16x16x32_bf16(
                    ones, bp[ks2], osum, 0, 0, 0);
#pragma unroll
                for (int db = 0; db < 4; ++db)
                    oaccT[db] = __builtin_amdgcn_mfma_f32_16x16x32_bf16(
                        av[db], bp[ks2], oaccT[db], 0, 0, 0);
                __builtin_amdgcn_s_setprio(0);
            }
        }
    }

    // epilogue: O^T/denom -> attn_out [b, t, h*64+d]; packed 8B stores.
    const int b = bh >> 4, h = bh & 15;
    const float inv = 1.0f / osum[0];
    const int t = q0 + wv * 16 + lo;
#pragma unroll
    for (int db = 0; db < 4; ++db) {
        bf16x4 o4;
#pragma unroll
        for (int r = 0; r < 4; ++r) o4[r] = (bf16)(oaccT[db][r] * inv);
        *(bf16x4*)(og + ((size_t)b * 2048 + t) * 1024 + h * 64 + db * 16 + quad * 4) = o4;
    }
}

// ---------------------------------------------------------------- launcher
extern "C" void kernel_launch(void* const* d_in, const int* in_sizes, int n_in,
                              void* d_out, int out_size, void* d_ws, size_t ws_size,
                              hipStream_t stream) {
    const float* x     = (const float*)d_in[0];
    const float* qkv_w = (const float*)d_in[1];
    const float* qkv_b = (const float*)d_in[2];
    const float* out_w = (const float*)d_in[3];
    const float* out_b = (const float*)d_in[4];
    float* out = (float*)d_out;
    char* ws = (char*)d_ws;
    // ws layout (48 MB total)
    bf16* xb  = (bf16*)(ws);                       // 8 MB  [4096][1024]
    bf16* wqb = (bf16*)(ws + 8388608);             // 6 MB  [3072][1024]
    bf16* wob = (bf16*)(ws + 14680064);            // 2 MB  [1024][1024]
    bf16* qb  = (bf16*)(ws + 16777216);            // 8 MB  [b,h,t,d]
    bf16* kb  = (bf16*)(ws + 25165824);            // 8 MB  [b,h,t,d]
    bf16* vt  = (bf16*)(ws + 33554432);            // 8 MB  [b,h,d,t]
    bf16* ao  = (bf16*)(ws + 41943040);            // 8 MB  [4096][1024]

    k_convert<<<8192, 256, 0, stream>>>(x, qkv_w, out_w, xb, wqb, wob);
    k_gemm_qkv<<<dim3(24, 32), 256, 0, stream>>>(xb, wqb, qkv_b, qb, kb, vt);
    k_attn<<<dim3(16, 32), 512, 0, stream>>>(qb, kb, vt, ao);
    k_gemm_out<<<dim3(16, 32), 256, 0, stream>>>(ao, wob, out_b, out);
}